// Round 1
// baseline (532.960 us; speedup 1.0000x reference)
//
#include <hip/hip_runtime.h>

#define D 64

// ---------------- bf16 helpers ----------------
__device__ __forceinline__ float blo(unsigned u) { return __uint_as_float(u << 16); }
__device__ __forceinline__ float bhi(unsigned u) { return __uint_as_float(u & 0xffff0000u); }
__device__ __forceinline__ unsigned rne(float f) {
    unsigned u = __float_as_uint(f);
    return (u + 0x7fffu + ((u >> 16) & 1u)) >> 16;
}
__device__ __forceinline__ unsigned packbf(float a, float b) {
    unsigned ub = __float_as_uint(b);
    return rne(a) | ((ub + 0x7fffu + ((ub >> 16) & 1u)) & 0xffff0000u);
}
__device__ __forceinline__ void add4(float4* p, float a, float b, float c, float d) {
    float4 o = *p; o.x += a; o.y += b; o.z += c; o.w += d; *p = o;
}

__global__ void to_bf16_kernel(const float* __restrict__ u, const float* __restrict__ b,
                               const float* __restrict__ it,
                               unsigned* __restrict__ SU, unsigned* __restrict__ SB,
                               unsigned* __restrict__ SI, int nU2, int nB2, int nI2) {
    int i = blockIdx.x * 256 + threadIdx.x;
    if (i < nU2) {
        float2 f = ((const float2*)u)[i];
        SU[i] = packbf(f.x, f.y);
    } else if (i < nU2 + nB2) {
        int j = i - nU2;
        float2 f = ((const float2*)b)[j];
        SB[j] = packbf(f.x, f.y);
    } else if (i < nU2 + nB2 + nI2) {
        int j = i - nU2 - nB2;
        float2 f = ((const float2*)it)[j];
        SI[j] = packbf(f.x, f.y);
    }
}

// ---------------- fused 3-graph CSR build, 512 buckets/graph ----------------
__global__ void hist_kernel(const int* __restrict__ r0, const int* __restrict__ r1,
                            const int* __restrict__ r2,
                            int ne0, int ne1, int ne2, int n0, int n1, int n2,
                            int* __restrict__ histG) {
    __shared__ int h[512];
    int t = threadIdx.x;
    int g = blockIdx.x >> 8, blk = blockIdx.x & 255;
    const int* rows = (g == 0) ? r0 : (g == 1) ? r1 : r2;
    int ne = (g == 0) ? ne0 : (g == 1) ? ne1 : ne2;
    unsigned n = (unsigned)((g == 0) ? n0 : (g == 1) ? n1 : n2);
    h[t] = 0; h[t + 256] = 0;
    __syncthreads();
    int C = (ne + 255) >> 8;
    int e0 = blk * C, e1 = min(ne, e0 + C);
    for (int e = e0 + t; e < e1; e += 256) {
        unsigned b = ((unsigned)rows[e] << 9) / n;
        atomicAdd(&h[b], 1);
    }
    __syncthreads();
    histG[(((g << 9) | t) << 8) | blk] = h[t];
    histG[(((g << 9) | (t + 256)) << 8) | blk] = h[t + 256];
}

__global__ void scan1_kernel(const int* __restrict__ deg, int* __restrict__ rs,
                             int* __restrict__ bsum, int n) {
    __shared__ int tmp[256];
    int t = threadIdx.x;
    int g = blockIdx.x * 256 + t;
    int v = (g < n) ? deg[g] : 0;
    tmp[t] = v;
    __syncthreads();
    for (int off = 1; off < 256; off <<= 1) {
        int x = (t >= off) ? tmp[t - off] : 0;
        __syncthreads();
        tmp[t] += x;
        __syncthreads();
    }
    if (g < n) rs[g] = tmp[t] - v;
    if (t == 255) bsum[blockIdx.x] = tmp[255];
}

__global__ void scan2_kernel(int* __restrict__ bsum, int B) {
    __shared__ int tmp[2048];
    int t = threadIdx.x;
    int v0 = (t < B) ? bsum[t] : 0;
    int v1 = (t + 1024 < B) ? bsum[t + 1024] : 0;
    tmp[t] = v0; tmp[t + 1024] = v1;
    __syncthreads();
    for (int off = 1; off < 2048; off <<= 1) {
        int a0 = (t >= off) ? tmp[t - off] : 0;
        int a1 = ((t + 1024) >= off) ? tmp[t + 1024 - off] : 0;
        __syncthreads();
        tmp[t] += a0; tmp[t + 1024] += a1;
        __syncthreads();
    }
    if (t < B) bsum[t] = tmp[t] - v0;
    if (t + 1024 < B) bsum[t + 1024] = tmp[t + 1024] - v1;
}

__global__ void scan3_kernel(int* __restrict__ rs, const int* __restrict__ bsum, int n) {
    int g = blockIdx.x * blockDim.x + threadIdx.x;
    if (g < n) rs[g] += bsum[g >> 8];
}

__global__ void bucket_scatter_kernel(const int* __restrict__ r0, const int* __restrict__ c0,
                                      const int* __restrict__ r1, const int* __restrict__ c1,
                                      const int* __restrict__ r2, const int* __restrict__ c2,
                                      int ne0, int ne1, int ne2, int n0, int n1, int n2,
                                      const int* __restrict__ hofs, unsigned* __restrict__ ebuf) {
    __shared__ int cur[512];
    int t = threadIdx.x;
    int g = blockIdx.x >> 8, blk = blockIdx.x & 255;
    const int* rows = (g == 0) ? r0 : (g == 1) ? r1 : r2;
    const int* cols = (g == 0) ? c0 : (g == 1) ? c1 : c2;
    int ne = (g == 0) ? ne0 : (g == 1) ? ne1 : ne2;
    int n  = (g == 0) ? n0  : (g == 1) ? n1  : n2;
    cur[t] = hofs[(((g << 9) | t) << 8) | blk];
    cur[t + 256] = hofs[(((g << 9) | (t + 256)) << 8) | blk];
    __syncthreads();
    int C = (ne + 255) >> 8;
    int e0 = blk * C, e1 = min(ne, e0 + C);
    for (int e = e0 + t; e < e1; e += 256) {
        int r = rows[e];
        unsigned b = ((unsigned)r << 9) / (unsigned)n;
        int rb0 = ((int)b * n + 511) >> 9;
        int pos = atomicAdd(&cur[b], 1);
        ebuf[pos] = ((unsigned)(r - rb0) << 23) | (unsigned)cols[e];
    }
}

__global__ void sort_bucket_kernel(const unsigned* __restrict__ ebuf, const int* __restrict__ hofs,
                                   int* __restrict__ rs0, int* __restrict__ rs1, int* __restrict__ rs2,
                                   float* __restrict__ isd0, float* __restrict__ isd1,
                                   float* __restrict__ isd2, int* __restrict__ ccol,
                                   int ne0, int ne1, int ne2, int n0, int n1, int n2) {
    __shared__ int cnt[256];
    __shared__ int pfx[256];
    int t = threadIdx.x;
    int g = blockIdx.x >> 9, b = blockIdx.x & 511;
    int ne = (g == 0) ? ne0 : (g == 1) ? ne1 : ne2;
    int n  = (g == 0) ? n0  : (g == 1) ? n1  : n2;
    int O  = (g == 0) ? 0   : (g == 1) ? ne0 : ne0 + ne1;
    int*   rs  = (g == 0) ? rs0  : (g == 1) ? rs1  : rs2;
    float* isd = (g == 0) ? isd0 : (g == 1) ? isd1 : isd2;
    int rb0 = (b * n + 511) >> 9;
    int rb1 = ((b + 1) * n + 511) >> 9;
    int R = rb1 - rb0;
    cnt[t] = 0;
    __syncthreads();
    int base = hofs[((g << 9) | b) << 8];
    int end  = (b == 511) ? (O + ne) : hofs[((g << 9) | (b + 1)) << 8];
    for (int e = base + t; e < end; e += 256)
        atomicAdd(&cnt[ebuf[e] >> 23], 1);
    __syncthreads();
    pfx[t] = cnt[t];
    __syncthreads();
    for (int off = 1; off < 256; off <<= 1) {
        int v = (t >= off) ? pfx[t - off] : 0;
        __syncthreads();
        pfx[t] += v;
        __syncthreads();
    }
    int c0 = cnt[t], ex = pfx[t] - c0;
    if (t < R) {
        rs[rb0 + t] = base + ex - O;
        isd[rb0 + t] = 1.0f / (sqrtf((float)c0) + 1e-8f);
    }
    __syncthreads();
    cnt[t] = base + ex;
    __syncthreads();
    for (int e = base + t; e < end; e += 256) {
        unsigned p = ebuf[e];
        int pos = atomicAdd(&cnt[p >> 23], 1);
        ccol[pos] = (int)(p & 0x7fffffu);
    }
    if (b == 511 && t == 0) rs[n] = ne;
}

// ---------------- gather-SpMM: one 8-lane group per ROW (no SpMM reduction) ----------------
// lane q of a group owns dims 8q..8q+7 (one uint4 of bf16 per edge). 8 rows/wave.
// x4 predicated quad loop (clamped index + zero weight) + next-quad ccol prefetch:
// 4 independent feature gathers in flight per lane, no serial tail, no ccol on the
// dependent chain. Norm: 3 shfls (xor 1,2,4) within the group. Epilogue on all lanes.
struct GA {
    const int* rs; const int* ccol; const float* isd;
    const unsigned* srcA; const unsigned* srcB; int na;
    const float* inA; const float* inB;
    unsigned* feat_out; float* dst0; void* dst1;
    const float* coefs; const float* modalp; int mi; int n;
};

template <bool FIRST, bool A0, bool A1, bool BF16D1>
__launch_bounds__(256, 8)
__global__ void spmm_norm_kernel(GA A, GA B, int ntot) {
    int lane = threadIdx.x & 63;
    int row = (blockIdx.x * (blockDim.x >> 6) + (threadIdx.x >> 6)) * 8 + (lane >> 3);
    if (row >= ntot) return;
    GA G; int r;
    if (row < A.n) { G = A; r = row; }
    else           { G = B; r = row - A.n; if (r >= G.n) return; }
    int q = lane & 7;
    int s = G.rs[r], e = G.rs[r + 1];
    float isr = G.isd[r];
    const unsigned* src; int coff;
    if (FIRST && r < G.na) { src = G.srcB; coff = G.na; }
    else                   { src = G.srcA; coff = 0; }
    src += (q << 2);
    const int* cc = G.ccol;
    const float* isdp = G.isd;
    float a[8];
#pragma unroll
    for (int j = 0; j < 8; ++j) a[j] = 0.f;
    if (s < e) {
        int em1 = e - 1;
        int c0 = cc[s];
        int c1 = cc[min(s + 1, em1)];
        int c2 = cc[min(s + 2, em1)];
        int c3 = cc[min(s + 3, em1)];
        for (int k = s; k < e; k += 4) {
            uint4 f0 = *(const uint4*)(src + (size_t)(c0 - coff) * 32);
            uint4 f1 = *(const uint4*)(src + (size_t)(c1 - coff) * 32);
            uint4 f2 = *(const uint4*)(src + (size_t)(c2 - coff) * 32);
            uint4 f3 = *(const uint4*)(src + (size_t)(c3 - coff) * 32);
            float v0, v1, v2, v3;
            if (FIRST) {
                v0 = isdp[c0];
                v1 = (k + 1 < e) ? isdp[c1] : 0.f;
                v2 = (k + 2 < e) ? isdp[c2] : 0.f;
                v3 = (k + 3 < e) ? isdp[c3] : 0.f;
            } else {
                v0 = 1.f;
                v1 = (k + 1 < e) ? 1.f : 0.f;
                v2 = (k + 2 < e) ? 1.f : 0.f;
                v3 = (k + 3 < e) ? 1.f : 0.f;
            }
            int kn = k + 4;                       // prefetch next quad's indices
            c0 = cc[min(kn, em1)];
            c1 = cc[min(kn + 1, em1)];
            c2 = cc[min(kn + 2, em1)];
            c3 = cc[min(kn + 3, em1)];
            a[0] = fmaf(v0, blo(f0.x), a[0]); a[1] = fmaf(v0, bhi(f0.x), a[1]);
            a[2] = fmaf(v0, blo(f0.y), a[2]); a[3] = fmaf(v0, bhi(f0.y), a[3]);
            a[4] = fmaf(v0, blo(f0.z), a[4]); a[5] = fmaf(v0, bhi(f0.z), a[5]);
            a[6] = fmaf(v0, blo(f0.w), a[6]); a[7] = fmaf(v0, bhi(f0.w), a[7]);
            a[0] = fmaf(v1, blo(f1.x), a[0]); a[1] = fmaf(v1, bhi(f1.x), a[1]);
            a[2] = fmaf(v1, blo(f1.y), a[2]); a[3] = fmaf(v1, bhi(f1.y), a[3]);
            a[4] = fmaf(v1, blo(f1.z), a[4]); a[5] = fmaf(v1, bhi(f1.z), a[5]);
            a[6] = fmaf(v1, blo(f1.w), a[6]); a[7] = fmaf(v1, bhi(f1.w), a[7]);
            a[0] = fmaf(v2, blo(f2.x), a[0]); a[1] = fmaf(v2, bhi(f2.x), a[1]);
            a[2] = fmaf(v2, blo(f2.y), a[2]); a[3] = fmaf(v2, bhi(f2.y), a[3]);
            a[4] = fmaf(v2, blo(f2.z), a[4]); a[5] = fmaf(v2, bhi(f2.z), a[5]);
            a[6] = fmaf(v2, blo(f2.w), a[6]); a[7] = fmaf(v2, bhi(f2.w), a[7]);
            a[0] = fmaf(v3, blo(f3.x), a[0]); a[1] = fmaf(v3, bhi(f3.x), a[1]);
            a[2] = fmaf(v3, blo(f3.y), a[2]); a[3] = fmaf(v3, bhi(f3.y), a[3]);
            a[4] = fmaf(v3, blo(f3.z), a[4]); a[5] = fmaf(v3, bhi(f3.z), a[5]);
            a[6] = fmaf(v3, blo(f3.w), a[6]); a[7] = fmaf(v3, bhi(f3.w), a[7]);
        }
    }
    float s2 = 0.f;
#pragma unroll
    for (int j = 0; j < 8; ++j) s2 += a[j] * a[j];
    s2 += __shfl_xor(s2, 1, 64);
    s2 += __shfl_xor(s2, 2, 64);
    s2 += __shfl_xor(s2, 4, 64);
    float inv = 1.0f / fmaxf(sqrtf(s2), 1e-12f);   // scale-invariant: isr-free
    float mm = G.modalp[G.mi];
    size_t ro = (size_t)r * D + (q << 3);
    float ctb[8];
    if (FIRST) {
        float isr2 = isr * isr;                     // feat stored = isd_row * raw layer-1
        uint4 fw;
        fw.x = packbf(isr2 * a[0], isr2 * a[1]);
        fw.y = packbf(isr2 * a[2], isr2 * a[3]);
        fw.z = packbf(isr2 * a[4], isr2 * a[5]);
        fw.w = packbf(isr2 * a[6], isr2 * a[7]);
        *(uint4*)(G.feat_out + (size_t)r * 32 + (q << 2)) = fw;
        const float* ib = (r < G.na) ? (G.inA + ro) : (G.inB + (size_t)(r - G.na) * D + (q << 3));
        float4 a0 = *(const float4*)ib;
        float4 a1 = *(const float4*)(ib + 4);
        float c0 = G.coefs[0], c1m = G.coefs[1] * inv;
        ctb[0] = mm * fmaf(c0, a0.x, c1m * a[0]);
        ctb[1] = mm * fmaf(c0, a0.y, c1m * a[1]);
        ctb[2] = mm * fmaf(c0, a0.z, c1m * a[2]);
        ctb[3] = mm * fmaf(c0, a0.w, c1m * a[3]);
        ctb[4] = mm * fmaf(c0, a1.x, c1m * a[4]);
        ctb[5] = mm * fmaf(c0, a1.y, c1m * a[5]);
        ctb[6] = mm * fmaf(c0, a1.z, c1m * a[6]);
        ctb[7] = mm * fmaf(c0, a1.w, c1m * a[7]);
    } else {
        float mc = mm * G.coefs[2] * inv;
#pragma unroll
        for (int j = 0; j < 8; ++j) ctb[j] = mc * a[j];
    }
    if (r < G.na) {
        if (A0) {
            *(float4*)(G.dst0 + ro) = make_float4(ctb[0], ctb[1], ctb[2], ctb[3]);
            *(float4*)(G.dst0 + ro + 4) = make_float4(ctb[4], ctb[5], ctb[6], ctb[7]);
        } else {
            add4((float4*)(G.dst0 + ro), ctb[0], ctb[1], ctb[2], ctb[3]);
            add4((float4*)(G.dst0 + ro + 4), ctb[4], ctb[5], ctb[6], ctb[7]);
        }
    } else if (BF16D1) {
        unsigned* p = (unsigned*)G.dst1 + (size_t)(r - G.na) * 32 + (q << 2);
        if (!A1) {
            uint4 cur = *(const uint4*)p;
            ctb[0] += blo(cur.x); ctb[1] += bhi(cur.x);
            ctb[2] += blo(cur.y); ctb[3] += bhi(cur.y);
            ctb[4] += blo(cur.z); ctb[5] += bhi(cur.z);
            ctb[6] += blo(cur.w); ctb[7] += bhi(cur.w);
        }
        uint4 w;
        w.x = packbf(ctb[0], ctb[1]); w.y = packbf(ctb[2], ctb[3]);
        w.z = packbf(ctb[4], ctb[5]); w.w = packbf(ctb[6], ctb[7]);
        *(uint4*)p = w;
    } else {
        float* d1 = (float*)G.dst1 + (size_t)(r - G.na) * D + (q << 3);
        add4((float4*)d1, ctb[0], ctb[1], ctb[2], ctb[3]);
        add4((float4*)(d1 + 4), ctb[4], ctb[5], ctb[6], ctb[7]);
    }
}

// merged cross-aggs, 8-lane group per row — zero shuffles; same x4 predicated quad loop
__launch_bounds__(256, 8)
__global__ void agg2_kernel(const int* __restrict__ rsA, const int* __restrict__ ccA,
                            const unsigned* __restrict__ sA, float* __restrict__ oA,
                            int naA, int nA,
                            const int* __restrict__ rsB, const int* __restrict__ ccB,
                            const unsigned* __restrict__ sB, float* __restrict__ oB,
                            int naB, int nB) {
    int lane = threadIdx.x & 63;
    int row = (blockIdx.x * (blockDim.x >> 6) + (threadIdx.x >> 6)) * 8 + (lane >> 3);
    if (row >= nA + nB) return;
    const int* rs; const int* cc; const unsigned* src; float* out; int na; int r;
    if (row < nA) { rs = rsA; cc = ccA; src = sA; out = oA; na = naA; r = row; }
    else          { rs = rsB; cc = ccB; src = sB; out = oB; na = naB; r = row - nA; }
    int q = lane & 7;
    src += (q << 2);
    int s = rs[r], e = rs[r + 1];
    float a[8];
#pragma unroll
    for (int j = 0; j < 8; ++j) a[j] = 0.f;
    if (s < e) {
        int em1 = e - 1;
        int c0 = cc[s] - na;
        int c1 = cc[min(s + 1, em1)] - na;
        int c2 = cc[min(s + 2, em1)] - na;
        int c3 = cc[min(s + 3, em1)] - na;
        for (int k = s; k < e; k += 4) {
            uint4 f0 = *(const uint4*)(src + (size_t)c0 * 32);
            uint4 f1 = *(const uint4*)(src + (size_t)c1 * 32);
            uint4 f2 = *(const uint4*)(src + (size_t)c2 * 32);
            uint4 f3 = *(const uint4*)(src + (size_t)c3 * 32);
            float v1 = (k + 1 < e) ? 1.f : 0.f;
            float v2 = (k + 2 < e) ? 1.f : 0.f;
            float v3 = (k + 3 < e) ? 1.f : 0.f;
            int kn = k + 4;                       // prefetch next quad's indices
            c0 = cc[min(kn, em1)] - na;
            c1 = cc[min(kn + 1, em1)] - na;
            c2 = cc[min(kn + 2, em1)] - na;
            c3 = cc[min(kn + 3, em1)] - na;
            a[0] += blo(f0.x); a[1] += bhi(f0.x);
            a[2] += blo(f0.y); a[3] += bhi(f0.y);
            a[4] += blo(f0.z); a[5] += bhi(f0.z);
            a[6] += blo(f0.w); a[7] += bhi(f0.w);
            a[0] = fmaf(v1, blo(f1.x), a[0]); a[1] = fmaf(v1, bhi(f1.x), a[1]);
            a[2] = fmaf(v1, blo(f1.y), a[2]); a[3] = fmaf(v1, bhi(f1.y), a[3]);
            a[4] = fmaf(v1, blo(f1.z), a[4]); a[5] = fmaf(v1, bhi(f1.z), a[5]);
            a[6] = fmaf(v1, blo(f1.w), a[6]); a[7] = fmaf(v1, bhi(f1.w), a[7]);
            a[0] = fmaf(v2, blo(f2.x), a[0]); a[1] = fmaf(v2, bhi(f2.x), a[1]);
            a[2] = fmaf(v2, blo(f2.y), a[2]); a[3] = fmaf(v2, bhi(f2.y), a[3]);
            a[4] = fmaf(v2, blo(f2.z), a[4]); a[5] = fmaf(v2, bhi(f2.z), a[5]);
            a[6] = fmaf(v2, blo(f2.w), a[6]); a[7] = fmaf(v2, bhi(f2.w), a[7]);
            a[0] = fmaf(v3, blo(f3.x), a[0]); a[1] = fmaf(v3, bhi(f3.x), a[1]);
            a[2] = fmaf(v3, blo(f3.y), a[2]); a[3] = fmaf(v3, bhi(f3.y), a[3]);
            a[4] = fmaf(v3, blo(f3.z), a[4]); a[5] = fmaf(v3, bhi(f3.z), a[5]);
            a[6] = fmaf(v3, blo(f3.w), a[6]); a[7] = fmaf(v3, bhi(f3.w), a[7]);
        }
    }
    float ad = 1.0f / ((float)(e - s) + 1e-8f);
    float* p = out + (size_t)r * D + (q << 3);
    add4((float4*)p, ad * a[0], ad * a[1], ad * a[2], ad * a[3]);
    add4((float4*)(p + 4), ad * a[4], ad * a[5], ad * a[6], ad * a[7]);
}

extern "C" void kernel_launch(void* const* d_in, const int* in_sizes, int n_in,
                              void* d_out, int out_size, void* d_ws, size_t ws_size,
                              hipStream_t stream) {
    const float* users   = (const float*)d_in[0];
    const float* bundles = (const float*)d_in[1];
    const float* items   = (const float*)d_in[2];
    const int*   ub_rows = (const int*)d_in[3];
    const int*   ub_cols = (const int*)d_in[4];
    const int*   ui_rows = (const int*)d_in[6];
    const int*   ui_cols = (const int*)d_in[7];
    const int*   bi_rows = (const int*)d_in[9];
    const int*   bi_cols = (const int*)d_in[10];
    const float* ub_coefs = (const float*)d_in[18];
    const float* ui_coefs = (const float*)d_in[19];
    const float* bi_coefs = (const float*)d_in[20];
    const float* modal    = (const float*)d_in[21];

    const int NU_ = in_sizes[0] / D;
    const int NB_ = in_sizes[1] / D;
    const int NI_ = in_sizes[2] / D;
    const int ne_ub = in_sizes[3];
    const int ne_ui = in_sizes[6];
    const int ne_bi = in_sizes[9];

    const int n_ui = NU_ + NI_;
    const int n_bi = NB_ + NI_;
    const int n_ub = NU_ + NB_;

    float* out = (float*)d_out;

    // ws layout (4B units), total 16,956,224 = 67.8 MB:
    int*      rs_ui  = (int*)d_ws;
    int*      rs_bi  = rs_ui + 90112;
    int*      rs_ub  = rs_bi + 70144;
    float*    isd_ui = (float*)(rs_ub + 40192);
    float*    isd_bi = isd_ui + 90112;
    float*    isd_ub = isd_bi + 70144;
    int*      hofs   = (int*)(isd_ub + 40192);
    int*      bsum   = hofs + 393280;
    int*      ccol   = bsum + 2048;
    int*      histG  = ccol;                       // aliases ccol (dead before sort writes)
    unsigned* SU     = (unsigned*)(ccol + 4000000);
    unsigned* SB     = SU + 960000;
    unsigned* SI     = SB + 320000;
    unsigned* ovl    = SI + 1920000;
    unsigned* ebuf   = ovl;
    unsigned* sfB_ui = ovl;
    unsigned* sfB_bi = sfB_ui + 2880000;
    unsigned* IT1b   = sfB_bi + 2240000;
    unsigned* IT2b   = IT1b + 1920000;
    unsigned* sfB_ub = IT1b;                       // aliases IT1b (dead after aggs)

    int* ccol_ui = ccol;
    int* ccol_bi = ccol + ne_ui;
    int* ccol_ub = ccol + ne_ui + ne_bi;

    float* out_u = out;
    float* out_b = out + (size_t)NU_ * D;

    {
        int tot2 = (NU_ + NB_ + NI_) * 32;
        to_bf16_kernel<<<(tot2 + 255) / 256, 256, 0, stream>>>(
            users, bundles, items, SU, SB, SI, NU_ * 32, NB_ * 32, NI_ * 32);
    }

    hist_kernel<<<768, 256, 0, stream>>>(ui_rows, bi_rows, ub_rows,
                                         ne_ui, ne_bi, ne_ub, n_ui, n_bi, n_ub, histG);
    scan1_kernel<<<1536, 256, 0, stream>>>(histG, hofs, bsum, 393216);
    scan2_kernel<<<1, 1024, 0, stream>>>(bsum, 1536);
    scan3_kernel<<<1536, 256, 0, stream>>>(hofs, bsum, 393216);
    bucket_scatter_kernel<<<768, 256, 0, stream>>>(
        ui_rows, ui_cols, bi_rows, bi_cols, ub_rows, ub_cols,
        ne_ui, ne_bi, ne_ub, n_ui, n_bi, n_ub, hofs, ebuf);
    sort_bucket_kernel<<<1536, 256, 0, stream>>>(
        ebuf, hofs, rs_ui, rs_bi, rs_ub, isd_ui, isd_bi, isd_ub, ccol,
        ne_ui, ne_bi, ne_ub, n_ui, n_bi, n_ub);

    GA gUI = { rs_ui, ccol_ui, isd_ui, SU, SI, NU_, users, items,
               sfB_ui, out_u, (void*)IT1b, ui_coefs, modal, 1, n_ui };
    GA gBI = { rs_bi, ccol_bi, isd_bi, SB, SI, NB_, bundles, items,
               sfB_bi, out_b, (void*)IT2b, bi_coefs, modal, 2, n_bi };
    GA gUB = { rs_ub, ccol_ub, isd_ub, SU, SB, NU_, users, bundles,
               sfB_ub, out_u, (void*)out_b, ub_coefs, modal, 0, n_ub };
    GA gUI2 = gUI; gUI2.srcA = sfB_ui;
    GA gBI2 = gBI; gBI2.srcA = sfB_bi;
    GA gUB2 = gUB; gUB2.srcA = sfB_ub;

    int ntotL = n_ui + n_bi;
    // 32 rows per block (4 waves x 8 rows)
    spmm_norm_kernel<true,  true,  true,  true ><<<(ntotL + 31) / 32, 256, 0, stream>>>(gUI,  gBI,  ntotL);
    spmm_norm_kernel<false, false, false, true ><<<(ntotL + 31) / 32, 256, 0, stream>>>(gUI2, gBI2, ntotL);

    agg2_kernel<<<(NU_ + NB_ + 31) / 32, 256, 0, stream>>>(
        rs_ui, ccol_ui, IT2b, out_u, NU_, NU_,
        rs_bi, ccol_bi, IT1b, out_b, NB_, NB_);

    spmm_norm_kernel<true,  false, false, false><<<(n_ub + 31) / 32, 256, 0, stream>>>(gUB,  gUB,  n_ub);
    spmm_norm_kernel<false, false, false, false><<<(n_ub + 31) / 32, 256, 0, stream>>>(gUB2, gUB2, n_ub);
}